// Round 5
// baseline (164.453 us; speedup 1.0000x reference)
//
#include <hip/hip_runtime.h>
#include <hip/hip_bf16.h>

typedef short bf16x8 __attribute__((ext_vector_type(8)));  // 8 bf16 (4 VGPRs)
typedef float f32x4 __attribute__((ext_vector_type(4)));

#define S_LEN 2048
#define NHEAD 16
#define DM 1024

#if __has_builtin(__builtin_amdgcn_exp2f)
#define EXP2(x) __builtin_amdgcn_exp2f(x)
#else
#define EXP2(x) exp2f(x)
#endif

__device__ __forceinline__ short f2bf(float f) {
  union { float f; unsigned u; } x; x.f = f;
  unsigned r = x.u + 0x7fffu + ((x.u >> 16) & 1u);  // RNE
  return (short)(r >> 16);
}

// v_cvt_pk_bf16_f32: lo -> bits[15:0], hi -> bits[31:16], RNE
__device__ __forceinline__ unsigned cvt_pk_bf16(float lo, float hi) {
  unsigned r;
  asm("v_cvt_pk_bf16_f32 %0, %1, %2" : "=v"(r) : "v"(lo), "v"(hi));
  return r;
}

__device__ __forceinline__ void gload16(const void* g, void* l) {
  __builtin_amdgcn_global_load_lds(
      (const __attribute__((address_space(1))) void*)g,
      (__attribute__((address_space(3))) void*)l, 16, 0, 0);
}

// ---------------- weight transpose+convert: T[n][k] = bf16(W[k][n]), 1024x1024
__global__ __launch_bounds__(256) void wtrans(const float* __restrict__ Wq, const float* __restrict__ Wk,
                                              const float* __restrict__ Wv, const float* __restrict__ Wo,
                                              short* Tq, short* Tk, short* Tv, short* To) {
  const int z = blockIdx.z;
  const float* W = (z == 0) ? Wq : (z == 1) ? Wk : (z == 2) ? Wv : Wo;
  short* T = (z == 0) ? Tq : (z == 1) ? Tk : (z == 2) ? Tv : To;
  __shared__ short Tl[64][72];
  const int tid = threadIdx.x;
  const int k0 = blockIdx.x * 64, n0 = blockIdx.y * 64;
  const int r = tid >> 2, c0 = (tid & 3) * 16;
#pragma unroll
  for (int j = 0; j < 4; j++) {
    float4 v = *(const float4*)&W[(size_t)(k0 + r) * DM + n0 + c0 + 4 * j];
    Tl[r][c0 + 4 * j + 0] = f2bf(v.x);
    Tl[r][c0 + 4 * j + 1] = f2bf(v.y);
    Tl[r][c0 + 4 * j + 2] = f2bf(v.z);
    Tl[r][c0 + 4 * j + 3] = f2bf(v.w);
  }
  __syncthreads();
  bf16x8 o0, o1;
#pragma unroll
  for (int j = 0; j < 8; j++) { o0[j] = Tl[c0 + j][r]; o1[j] = Tl[c0 + 8 + j][r]; }
  *(bf16x8*)&T[(size_t)(n0 + r) * DM + k0 + c0] = o0;
  *(bf16x8*)&T[(size_t)(n0 + r) * DM + k0 + c0 + 8] = o1;
}

// ---------------- x f32 -> bf16 convert (3 tensors), 16 elems/thread
__global__ __launch_bounds__(256) void xcvt(const float* __restrict__ q, const float* __restrict__ k,
                                            const float* __restrict__ v,
                                            short* xq, short* xk, short* xv) {
  const int z = blockIdx.y;
  const float* src = (z == 0) ? q : (z == 1) ? k : v;
  short* dst = (z == 0) ? xq : (z == 1) ? xk : xv;
  const size_t base = ((size_t)blockIdx.x * 256 + threadIdx.x) * 16;
  float4 a = *(const float4*)&src[base];
  float4 b = *(const float4*)&src[base + 4];
  float4 c = *(const float4*)&src[base + 8];
  float4 d = *(const float4*)&src[base + 12];
  bf16x8 o0, o1;
  o0[0] = f2bf(a.x); o0[1] = f2bf(a.y); o0[2] = f2bf(a.z); o0[3] = f2bf(a.w);
  o0[4] = f2bf(b.x); o0[5] = f2bf(b.y); o0[6] = f2bf(b.z); o0[7] = f2bf(b.w);
  o1[0] = f2bf(c.x); o1[1] = f2bf(c.y); o1[2] = f2bf(c.z); o1[3] = f2bf(c.w);
  o1[4] = f2bf(d.x); o1[5] = f2bf(d.y); o1[6] = f2bf(d.z); o1[7] = f2bf(d.w);
  *(bf16x8*)&dst[base] = o0;
  *(bf16x8*)&dst[base + 8] = o1;
}

// ---------------- gemm3: all-bf16, global_load_lds dbuf, swizzled LDS.
// C(MxN) = A(MxK) @ B_op(KxN), A bf16 [m][k], Bt bf16 [n][k].
// BM=128 BN=64 BK=64, 256 thr (4 waves 2x2), per-wave 64x32 (acc 4x2).
template<int CM>
__global__ __launch_bounds__(256) void gemm3(const short* __restrict__ A, const short* __restrict__ Bt,
                                             void* __restrict__ Cp, int M, int N, int K) {
  __shared__ __align__(16) short Al[2][128 * 64];
  __shared__ __align__(16) short Bl[2][64 * 64];
  const int tid = threadIdx.x;
  const int lane = tid & 63, w = tid >> 6;
  const int wm = w >> 1, wn = w & 1;
  const int lr = lane & 15, g = lane >> 4;
  const int m0 = blockIdx.y * 128, n0 = blockIdx.x * 64;

  f32x4 acc[4][2];
#pragma unroll
  for (int i = 0; i < 4; i++)
#pragma unroll
    for (int j = 0; j < 2; j++) acc[i][j] = (f32x4){0.f, 0.f, 0.f, 0.f};

  const int srow = lane >> 3;
  const int sch = (lane & 7) ^ (srow & 7);
  const short* gA = A + (size_t)(m0 + w * 32 + srow) * K + 8 * sch;
  const short* gB = Bt + (size_t)(n0 + w * 16 + srow) * K + 8 * sch;

#define STAGE(buf, kk)                                                              \
  do {                                                                              \
    _Pragma("unroll") for (int c = 0; c < 4; c++)                                   \
        gload16(gA + (size_t)c * 8 * K + (kk), &Al[buf][(w * 32 + c * 8) * 64]);    \
    _Pragma("unroll") for (int c = 0; c < 2; c++)                                   \
        gload16(gB + (size_t)c * 8 * K + (kk), &Bl[buf][(w * 16 + c * 8) * 64]);    \
  } while (0)

  const int nsteps = K >> 6;
  STAGE(0, 0);
  int buf = 0;
  for (int t = 0; t < nsteps; t++) {
    __syncthreads();
    if (t + 1 < nsteps) STAGE(buf ^ 1, (t + 1) << 6);
#pragma unroll
    for (int kc = 0; kc < 2; kc++) {
      bf16x8 af[4], bfr[2];
#pragma unroll
      for (int mt = 0; mt < 4; mt++) {
        int row = wm * 64 + mt * 16 + lr;
        af[mt] = *(const bf16x8*)&Al[buf][row * 64 + 8 * ((kc * 4 + g) ^ (lr & 7))];
      }
#pragma unroll
      for (int nt = 0; nt < 2; nt++) {
        int row = wn * 32 + nt * 16 + lr;
        bfr[nt] = *(const bf16x8*)&Bl[buf][row * 64 + 8 * ((kc * 4 + g) ^ (lr & 7))];
      }
      __builtin_amdgcn_s_setprio(1);
#pragma unroll
      for (int mt = 0; mt < 4; mt++)
#pragma unroll
        for (int nt = 0; nt < 2; nt++)
          acc[mt][nt] = __builtin_amdgcn_mfma_f32_16x16x32_bf16(af[mt], bfr[nt], acc[mt][nt], 0, 0, 0);
      __builtin_amdgcn_s_setprio(0);
    }
    buf ^= 1;
  }
#undef STAGE

#pragma unroll
  for (int mt = 0; mt < 4; mt++)
#pragma unroll
    for (int nt = 0; nt < 2; nt++)
#pragma unroll
      for (int r = 0; r < 4; r++) {
        int row = m0 + wm * 64 + mt * 16 + g * 4 + r;
        int col = n0 + wn * 32 + nt * 16 + lr;
        if (CM == 0) {
          ((float*)Cp)[(size_t)row * N + col] = acc[mt][nt][r];
        } else if (CM == 1 || CM == 3) {
          float v = (CM == 3) ? acc[mt][nt][r] * 0.18033688011f : acc[mt][nt][r];
          int b = row >> 11, s = row & (S_LEN - 1);
          int h = col >> 6, d = col & 63;
          ((short*)Cp)[(((size_t)(b * NHEAD + h)) * S_LEN + s) * 64 + d] = f2bf(v);
        } else {
          int h = row >> 6, d = row & 63;
          int b = col >> 11, s = col & (S_LEN - 1);
          ((short*)Cp)[(((size_t)(b * NHEAD + h)) * 64 + d) * S_LEN + s] = f2bf(acc[mt][nt][r]);
        }
      }
}

// ---------------- gemm2 (reg-staged, fallback path for small ws)
template<int AM, int BMODE, int CM>
__global__ __launch_bounds__(256) void gemm2(const void* __restrict__ Ap, const void* __restrict__ Bp,
                                             void* __restrict__ Cp, int M, int N, int K) {
  __shared__ __align__(16) short Al[128][72];
  __shared__ __align__(16) short Bl[64][72];
  const int tid = threadIdx.x;
  const int lane = tid & 63, w = tid >> 6;
  const int wm = w >> 1, wn = w & 1;
  const int lr = lane & 15, g = lane >> 4;
  const int m0 = blockIdx.y * 128, n0 = blockIdx.x * 64;

  f32x4 acc[4][2];
#pragma unroll
  for (int i = 0; i < 4; i++)
#pragma unroll
    for (int j = 0; j < 2; j++) acc[i][j] = (f32x4){0.f, 0.f, 0.f, 0.f};

  const int ar = tid >> 1, ac = (tid & 1) * 32;
  const int br = tid >> 2, bc = (tid & 3) * 16;

  float4 la[8]; bf16x8 la8[4];
  float4 lb[4]; bf16x8 lb8[2];

#define LOADA(kk)                                                                        \
  do {                                                                                   \
    if (AM == 0) {                                                                       \
      const float* A = (const float*)Ap;                                                 \
      _Pragma("unroll") for (int j = 0; j < 8; j++)                                      \
          la[j] = *(const float4*)&A[(size_t)(m0 + ar) * K + (kk) + ac + 4 * j];         \
    } else {                                                                             \
      const short* A = (const short*)Ap;                                                 \
      _Pragma("unroll") for (int j = 0; j < 4; j++)                                      \
          la8[j] = *(const bf16x8*)&A[(size_t)(m0 + ar) * K + (kk) + ac + 8 * j];        \
    }                                                                                    \
  } while (0)

#define LOADB(kk)                                                                        \
  do {                                                                                   \
    if (BMODE == 0) {                                                                    \
      const float* B = (const float*)Bp;                                                 \
      _Pragma("unroll") for (int j = 0; j < 4; j++)                                      \
          lb[j] = *(const float4*)&B[(size_t)(n0 + br) * K + (kk) + bc + 4 * j];         \
    } else if (BMODE == 1) {                                                             \
      const short* B = (const short*)Bp;                                                 \
      _Pragma("unroll") for (int j = 0; j < 2; j++)                                      \
          lb8[j] = *(const bf16x8*)&B[(size_t)(n0 + br) * K + (kk) + bc + 8 * j];        \
    } else {                                                                             \
      const float* B = (const float*)Bp;                                                 \
      _Pragma("unroll") for (int j = 0; j < 4; j++)                                      \
          lb[j] = *(const float4*)&B[(size_t)((kk) + br) * N + n0 + bc + 4 * j];         \
    }                                                                                    \
  } while (0)

  const int nsteps = K >> 6;
  LOADA(0); LOADB(0);

  for (int t = 0; t < nsteps; t++) {
    __syncthreads();
    if (AM == 0) {
#pragma unroll
      for (int j = 0; j < 4; j++) {
        float4 v0 = la[2 * j], v1 = la[2 * j + 1];
        bf16x8 tt;
        tt[0] = f2bf(v0.x); tt[1] = f2bf(v0.y); tt[2] = f2bf(v0.z); tt[3] = f2bf(v0.w);
        tt[4] = f2bf(v1.x); tt[5] = f2bf(v1.y); tt[6] = f2bf(v1.z); tt[7] = f2bf(v1.w);
        *(bf16x8*)&Al[ar][ac + 8 * j] = tt;
      }
    } else {
#pragma unroll
      for (int j = 0; j < 4; j++) *(bf16x8*)&Al[ar][ac + 8 * j] = la8[j];
    }
    if (BMODE == 0) {
#pragma unroll
      for (int j = 0; j < 2; j++) {
        float4 v0 = lb[2 * j], v1 = lb[2 * j + 1];
        bf16x8 tt;
        tt[0] = f2bf(v0.x); tt[1] = f2bf(v0.y); tt[2] = f2bf(v0.z); tt[3] = f2bf(v0.w);
        tt[4] = f2bf(v1.x); tt[5] = f2bf(v1.y); tt[6] = f2bf(v1.z); tt[7] = f2bf(v1.w);
        *(bf16x8*)&Bl[br][bc + 8 * j] = tt;
      }
    } else if (BMODE == 1) {
#pragma unroll
      for (int j = 0; j < 2; j++) *(bf16x8*)&Bl[br][bc + 8 * j] = lb8[j];
    } else {
#pragma unroll
      for (int j = 0; j < 4; j++) {
        float4 v = lb[j];
        Bl[bc + 4 * j + 0][br] = f2bf(v.x);
        Bl[bc + 4 * j + 1][br] = f2bf(v.y);
        Bl[bc + 4 * j + 2][br] = f2bf(v.z);
        Bl[bc + 4 * j + 3][br] = f2bf(v.w);
      }
    }
    __syncthreads();
    if (t + 1 < nsteps) { LOADA((t + 1) << 6); LOADB((t + 1) << 6); }
#pragma unroll
    for (int kc = 0; kc < 2; kc++) {
      bf16x8 af[4], bfr[2];
#pragma unroll
      for (int mt = 0; mt < 4; mt++) af[mt] = *(const bf16x8*)&Al[wm * 64 + mt * 16 + lr][kc * 32 + g * 8];
#pragma unroll
      for (int nt = 0; nt < 2; nt++) bfr[nt] = *(const bf16x8*)&Bl[wn * 32 + nt * 16 + lr][kc * 32 + g * 8];
#pragma unroll
      for (int mt = 0; mt < 4; mt++)
#pragma unroll
        for (int nt = 0; nt < 2; nt++)
          acc[mt][nt] = __builtin_amdgcn_mfma_f32_16x16x32_bf16(af[mt], bfr[nt], acc[mt][nt], 0, 0, 0);
    }
  }
#undef LOADA
#undef LOADB

#pragma unroll
  for (int mt = 0; mt < 4; mt++)
#pragma unroll
    for (int nt = 0; nt < 2; nt++)
#pragma unroll
      for (int r = 0; r < 4; r++) {
        int row = m0 + wm * 64 + mt * 16 + g * 4 + r;
        int col = n0 + wn * 32 + nt * 16 + lr;
        if (CM == 0) {
          ((float*)Cp)[(size_t)row * N + col] = acc[mt][nt][r];
        } else if (CM == 1 || CM == 3) {
          float v = (CM == 3) ? acc[mt][nt][r] * 0.18033688011f : acc[mt][nt][r];
          int b = row >> 11, s = row & (S_LEN - 1);
          int h = col >> 6, d = col & 63;
          ((short*)Cp)[(((size_t)(b * NHEAD + h)) * S_LEN + s) * 64 + d] = f2bf(v);
        } else {
          int h = row >> 6, d = row & 63;
          int b = col >> 11, s = col & (S_LEN - 1);
          ((short*)Cp)[(((size_t)(b * NHEAD + h)) * 64 + d) * S_LEN + s] = f2bf(acc[mt][nt][r]);
        }
      }
}

// ---------------- Flash attention v5: QBLK=256 (4 waves x 64 q), KVBLK=64,
// 1 block/CU, swapped QK^T (S^T frags: q = lane&15, k = 4g+r), cvt_pk P-pack,
// b64 P writes, max-free exp2 softmax (Q pre-scaled by 0.125*log2e).
// Q,K: [bh][s][64] bf16.  V^T: [bh][64][s] bf16.
__global__ __launch_bounds__(256) void attn5(const short* __restrict__ Qb,
                                              const short* __restrict__ Kb,
                                              const short* __restrict__ VbT,
                                              const int* __restrict__ mask,
                                              short* __restrict__ Ob) {
  __shared__ __align__(16) short Kl[2][64][64];
  __shared__ __align__(16) short Vl[2][64][64];
  __shared__ __align__(16) short Pl[4][64][64];

  const int tid = threadIdx.x;
  const int lane = tid & 63, w = tid >> 6;  // 4 waves
  const int lr = lane & 15, g = lane >> 4;

  // XCD-chunked bijective swizzle: 256 blocks, 8 XCDs, 32/chunk -> 4 heads/XCD
  const int flat = blockIdx.y * gridDim.x + blockIdx.x;
  const int wid = (flat & 7) * 32 + (flat >> 3);
  const int qblk = wid & 7, bh = wid >> 3;
  const int b = bh >> 4, h = bh & 15;
  const int qbase = qblk * 256;
  const size_t hoff = (size_t)bh * S_LEN * 64;

  // Q frags: 64 q-rows per wave (4 x 16-frag), 64 d (2 k-halves)
  bf16x8 qf[4][2];
#pragma unroll
  for (int qfr = 0; qfr < 4; qfr++)
#pragma unroll
    for (int kh = 0; kh < 2; kh++)
      qf[qfr][kh] = *(const bf16x8*)&Qb[hoff + (size_t)(qbase + w * 64 + qfr * 16 + lr) * 64 + kh * 32 + g * 8];

  f32x4 o_acc[4][4];
  float lsum[4];
#pragma unroll
  for (int qfr = 0; qfr < 4; qfr++) {
    lsum[qfr] = 0.f;
#pragma unroll
    for (int dg = 0; dg < 4; dg++) o_acc[qfr][dg] = (f32x4){0.f, 0.f, 0.f, 0.f};
  }

  const int* maskb = mask + b * S_LEN;
  // staging: wave w covers rows [w*16, w*16+16) via 2 gload16 per tensor
  const int srow = lane >> 3;
  const int sch = (lane & 7) ^ (srow & 7);
  const short* gK = Kb + hoff + (size_t)(w * 16 + srow) * 64 + 8 * sch;
  const short* gV = VbT + hoff + (size_t)(w * 16 + srow) * S_LEN + 8 * sch;

#define STAGEKV(buf, kb)                                                         \
  do {                                                                           \
    _Pragma("unroll") for (int c = 0; c < 2; c++)                                \
        gload16(gK + (size_t)(kb + c * 8) * 64, &Kl[buf][w * 16 + c * 8][0]);    \
    _Pragma("unroll") for (int c = 0; c < 2; c++)                                \
        gload16(gV + (size_t)c * 8 * S_LEN + (kb), &Vl[buf][w * 16 + c * 8][0]); \
  } while (0)

  const int NT = S_LEN / 64;
  STAGEKV(0, 0);
  int buf = 0;

  for (int t = 0; t < NT; t++) {
    const int kb = t * 64;
    __syncthreads();  // vmcnt drained: tile t resident; prior reads of buf^1 done
    if (t + 1 < NT) STAGEKV(buf ^ 1, kb + 64);

    // mask bias: k = nt*16 + 4g + r
    float bias[4][4];
#pragma unroll
    for (int nt = 0; nt < 4; nt++) {
      int4 mv = *(const int4*)&maskb[kb + nt * 16 + 4 * g];
      bias[nt][0] = mv.x ? 0.f : -1e30f;
      bias[nt][1] = mv.y ? 0.f : -1e30f;
      bias[nt][2] = mv.z ? 0.f : -1e30f;
      bias[nt][3] = mv.w ? 0.f : -1e30f;
    }

    // K frags (A-operand): lane holds K[k = nt*16+lr][d = kh*32+8g..]
    bf16x8 kfr[4][2];
#pragma unroll
    for (int nt = 0; nt < 4; nt++)
#pragma unroll
      for (int kh = 0; kh < 2; kh++)
        kfr[nt][kh] = *(const bf16x8*)&Kl[buf][nt * 16 + lr][8 * ((4 * kh + g) ^ (lr & 7))];

    // V frags (B-operand)
    bf16x8 vfr[4][2];
#pragma unroll
    for (int dg = 0; dg < 4; dg++)
#pragma unroll
      for (int kh = 0; kh < 2; kh++)
        vfr[dg][kh] = *(const bf16x8*)&Vl[buf][dg * 16 + lr][8 * ((4 * kh + g) ^ (lr & 7))];

    // ---- per q-frag: swapped QK^T -> softmax -> P pack/store
#pragma unroll
    for (int qfr = 0; qfr < 4; qfr++) {
      f32x4 s[4];
#pragma unroll
      for (int nt = 0; nt < 4; nt++) s[nt] = (f32x4){0.f, 0.f, 0.f, 0.f};
      __builtin_amdgcn_s_setprio(1);
#pragma unroll
      for (int nt = 0; nt < 4; nt++) {
        s[nt] = __builtin_amdgcn_mfma_f32_16x16x32_bf16(kfr[nt][0], qf[qfr][0], s[nt], 0, 0, 0);
        s[nt] = __builtin_amdgcn_mfma_f32_16x16x32_bf16(kfr[nt][1], qf[qfr][1], s[nt], 0, 0, 0);
      }
      __builtin_amdgcn_s_setprio(0);
#pragma unroll
      for (int nt = 0; nt < 4; nt++) {
        float p0 = EXP2(s[nt][0] + bias[nt][0]);
        float p1 = EXP2(s[nt][1] + bias[nt][1]);
        float p2 = EXP2(s[nt][2] + bias[nt][2]);
        float p3 = EXP2(s[nt][3] + bias[nt][3]);
        lsum[qfr] += (p0 + p1) + (p2 + p3);
        uint2 pk;
        pk.x = cvt_pk_bf16(p0, p1);
        pk.y = cvt_pk_bf16(p2, p3);
        // P[q = qfr*16+lr][k0 = 16nt+4g], swizzle idx ^= (q&7)<<3
        *(uint2*)&Pl[w][qfr * 16 + lr][(16 * nt + 4 * g) ^ ((lr & 7) << 3)] = pk;
      }
    }

    // ---- PV
#pragma unroll
    for (int qfr = 0; qfr < 4; qfr++) {
      bf16x8 pf[2];
#pragma unroll
      for (int kh = 0; kh < 2; kh++)
        pf[kh] = *(const bf16x8*)&Pl[w][qfr * 16 + lr][(kh * 32 + 8 * g) ^ ((lr & 7) << 3)];
      __builtin_amdgcn_s_setprio(1);
#pragma unroll
      for (int dg = 0; dg < 4; dg++) {
        o_acc[qfr][dg] = __builtin_amdgcn_mfma_f32_16x16x32_bf16(pf[0], vfr[dg][0], o_acc[qfr][dg], 0, 0, 0);
        o_acc[qfr][dg] = __builtin_amdgcn_mfma_f32_16x16x32_bf16(pf[1], vfr[dg][1], o_acc[qfr][dg], 0, 0, 0);
      }
      __builtin_amdgcn_s_setprio(0);
    }
    buf ^= 1;
  }
#undef STAGEKV

  // ---- epilogue: lsum held per-lane for q=lr (partial over this lane's k);
  // reduce across g (xor 16, 32), then transpose inv to q=4g+r via shfl.
#pragma unroll
  for (int qfr = 0; qfr < 4; qfr++) {
    float l = lsum[qfr];
    l += __shfl_xor(l, 16);
    l += __shfl_xor(l, 32);
    float inv = 1.f / l;
    float invq[4];
#pragma unroll
    for (int r = 0; r < 4; r++) invq[r] = __shfl(inv, 4 * g + r);
#pragma unroll
    for (int dg = 0; dg < 4; dg++)
#pragma unroll
      for (int r = 0; r < 4; r++) {
        int qr = qbase + w * 64 + qfr * 16 + 4 * g + r;
        int col = h * 64 + dg * 16 + lr;
        Ob[((size_t)b * S_LEN + qr) * DM + col] = f2bf(o_acc[qfr][dg][r] * invq[r]);
      }
  }
}

extern "C" void kernel_launch(void* const* d_in, const int* in_sizes, int n_in,
                              void* d_out, int out_size, void* d_ws, size_t ws_size,
                              hipStream_t stream) {
  const float* query = (const float*)d_in[0];
  const float* key   = (const float*)d_in[1];
  const float* value = (const float*)d_in[2];
  const float* Wq = (const float*)d_in[3];
  const float* Wk = (const float*)d_in[4];
  const float* Wv = (const float*)d_in[5];
  const float* Wo = (const float*)d_in[6];
  const int* mask = (const int*)d_in[7];

  char* ws = (char*)d_ws;
  const size_t MB = 1 << 20;
  const bool big = ws_size >= 41 * MB;

  dim3 ag(S_LEN / 256, 2 * NHEAD);  // (8, 32) = 256 blocks

  if (big) {
    short* xq  = (short*)(ws);
    short* xk  = (short*)(ws + 8 * MB);
    short* xv  = (short*)(ws + 16 * MB);
    short* WqT = (short*)(ws + 24 * MB);
    short* WkT = (short*)(ws + 26 * MB);
    short* WvT = (short*)(ws + 28 * MB);
    short* WoT = (short*)(ws + 30 * MB);
    short* Qb  = (short*)(ws + 32 * MB);
    short* Kb  = xq;
    short* VbT = xk;
    short* Ob  = xv;

    dim3 tgrid(16, 16, 4);
    wtrans<<<tgrid, 256, 0, stream>>>(Wq, Wk, Wv, Wo, WqT, WkT, WvT, WoT);
    dim3 cg(1024, 3);
    xcvt<<<cg, 256, 0, stream>>>(query, key, value, xq, xk, xv);

    dim3 gqk(DM / 64, (2 * S_LEN) / 128);  // (16, 32)
    gemm3<3><<<gqk, 256, 0, stream>>>(xq, WqT, Qb, 2 * S_LEN, DM, DM);
    gemm3<1><<<gqk, 256, 0, stream>>>(xk, WkT, Kb, 2 * S_LEN, DM, DM);
    dim3 gv((2 * S_LEN) / 64, DM / 128);   // (64, 8)
    gemm3<2><<<gv, 256, 0, stream>>>(WvT, xv, VbT, DM, 2 * S_LEN, DM);

    attn5<<<ag, 256, 0, stream>>>(Qb, Kb, VbT, mask, Ob);

    gemm3<0><<<gqk, 256, 0, stream>>>(Ob, WoT, (float*)d_out, 2 * S_LEN, DM, DM);
  } else {
    short* Qb  = (short*)(ws);
    short* Kb  = (short*)(ws + 8 * MB);
    short* VbT = (short*)(ws + 16 * MB);
    short* WqT = (short*)(ws + 24 * MB);
    short* WkT = (short*)(ws + 26 * MB);
    short* WvT = (short*)(ws + 28 * MB);
    short* Ob  = (short*)(ws + 24 * MB);  // aliases dead WqT/WkT/WvT

    dim3 tgrid(16, 16, 3);
    wtrans<<<tgrid, 256, 0, stream>>>(Wq, Wk, Wv, Wo, WqT, WkT, WvT, WqT);

    dim3 gq(DM / 64, (2 * S_LEN) / 128);
    gemm2<0, 1, 3><<<gq, 256, 0, stream>>>(query, WqT, Qb, 2 * S_LEN, DM, DM);
    gemm2<0, 1, 1><<<gq, 256, 0, stream>>>(key,   WkT, Kb, 2 * S_LEN, DM, DM);
    dim3 gv((2 * S_LEN) / 64, DM / 128);
    gemm2<1, 0, 2><<<gv, 256, 0, stream>>>(WvT, value, VbT, DM, 2 * S_LEN, DM);

    attn5<<<ag, 256, 0, stream>>>(Qb, Kb, VbT, mask, Ob);

    gemm2<1, 2, 0><<<gq, 256, 0, stream>>>(Ob, Wo, (float*)d_out, 2 * S_LEN, DM, DM);
  }
}

// Round 6
// 137.422 us; speedup vs baseline: 1.1967x; 1.1967x over previous
//
#include <hip/hip_runtime.h>
#include <hip/hip_bf16.h>

typedef short bf16x8 __attribute__((ext_vector_type(8)));  // 8 bf16 (4 VGPRs)
typedef float f32x4 __attribute__((ext_vector_type(4)));

#define S_LEN 2048
#define NHEAD 16
#define DM 1024

#if __has_builtin(__builtin_amdgcn_exp2f)
#define EXP2(x) __builtin_amdgcn_exp2f(x)
#else
#define EXP2(x) exp2f(x)
#endif

__device__ __forceinline__ short f2bf(float f) {
  union { float f; unsigned u; } x; x.f = f;
  unsigned r = x.u + 0x7fffu + ((x.u >> 16) & 1u);  // RNE
  return (short)(r >> 16);
}

// v_cvt_pk_bf16_f32: lo -> bits[15:0], hi -> bits[31:16], RNE
__device__ __forceinline__ unsigned cvt_pk_bf16(float lo, float hi) {
  unsigned r;
  asm("v_cvt_pk_bf16_f32 %0, %1, %2" : "=v"(r) : "v"(lo), "v"(hi));
  return r;
}

// after: a = [A.L32, B.L32], b = [A.U32, B.U32]
__device__ __forceinline__ void pl32swap(unsigned& a, unsigned& b) {
#if __has_builtin(__builtin_amdgcn_permlane32_swap)
  auto r = __builtin_amdgcn_permlane32_swap(a, b, false, false);
  a = r[0]; b = r[1];
#else
  asm volatile("v_permlane32_swap_b32 %0, %1" : "+v"(a), "+v"(b));
#endif
}
// after (16-lane rows r0..r3): a = [A0,B0,A2,B2], b = [A1,B1,A3,B3]
__device__ __forceinline__ void pl16swap(unsigned& a, unsigned& b) {
#if __has_builtin(__builtin_amdgcn_permlane16_swap)
  auto r = __builtin_amdgcn_permlane16_swap(a, b, false, false);
  a = r[0]; b = r[1];
#else
  asm volatile("v_permlane16_swap_b32 %0, %1" : "+v"(a), "+v"(b));
#endif
}

__device__ __forceinline__ void gload16(const void* g, void* l) {
  __builtin_amdgcn_global_load_lds(
      (const __attribute__((address_space(1))) void*)g,
      (__attribute__((address_space(3))) void*)l, 16, 0, 0);
}

// ---------------- weight transpose+convert: T[n][k] = bf16(W[k][n]), 1024x1024
__global__ __launch_bounds__(256) void wtrans(const float* __restrict__ Wq, const float* __restrict__ Wk,
                                              const float* __restrict__ Wv, const float* __restrict__ Wo,
                                              short* Tq, short* Tk, short* Tv, short* To) {
  const int z = blockIdx.z;
  const float* W = (z == 0) ? Wq : (z == 1) ? Wk : (z == 2) ? Wv : Wo;
  short* T = (z == 0) ? Tq : (z == 1) ? Tk : (z == 2) ? Tv : To;
  __shared__ short Tl[64][72];
  const int tid = threadIdx.x;
  const int k0 = blockIdx.x * 64, n0 = blockIdx.y * 64;
  const int r = tid >> 2, c0 = (tid & 3) * 16;
#pragma unroll
  for (int j = 0; j < 4; j++) {
    float4 v = *(const float4*)&W[(size_t)(k0 + r) * DM + n0 + c0 + 4 * j];
    Tl[r][c0 + 4 * j + 0] = f2bf(v.x);
    Tl[r][c0 + 4 * j + 1] = f2bf(v.y);
    Tl[r][c0 + 4 * j + 2] = f2bf(v.z);
    Tl[r][c0 + 4 * j + 3] = f2bf(v.w);
  }
  __syncthreads();
  bf16x8 o0, o1;
#pragma unroll
  for (int j = 0; j < 8; j++) { o0[j] = Tl[c0 + j][r]; o1[j] = Tl[c0 + 8 + j][r]; }
  *(bf16x8*)&T[(size_t)(n0 + r) * DM + k0 + c0] = o0;
  *(bf16x8*)&T[(size_t)(n0 + r) * DM + k0 + c0 + 8] = o1;
}

// ---------------- x f32 -> bf16 convert (3 tensors), 16 elems/thread
__global__ __launch_bounds__(256) void xcvt(const float* __restrict__ q, const float* __restrict__ k,
                                            const float* __restrict__ v,
                                            short* xq, short* xk, short* xv) {
  const int z = blockIdx.y;
  const float* src = (z == 0) ? q : (z == 1) ? k : v;
  short* dst = (z == 0) ? xq : (z == 1) ? xk : xv;
  const size_t base = ((size_t)blockIdx.x * 256 + threadIdx.x) * 16;
  float4 a = *(const float4*)&src[base];
  float4 b = *(const float4*)&src[base + 4];
  float4 c = *(const float4*)&src[base + 8];
  float4 d = *(const float4*)&src[base + 12];
  bf16x8 o0, o1;
  o0[0] = f2bf(a.x); o0[1] = f2bf(a.y); o0[2] = f2bf(a.z); o0[3] = f2bf(a.w);
  o0[4] = f2bf(b.x); o0[5] = f2bf(b.y); o0[6] = f2bf(b.z); o0[7] = f2bf(b.w);
  o1[0] = f2bf(c.x); o1[1] = f2bf(c.y); o1[2] = f2bf(c.z); o1[3] = f2bf(c.w);
  o1[4] = f2bf(d.x); o1[5] = f2bf(d.y); o1[6] = f2bf(d.z); o1[7] = f2bf(d.w);
  *(bf16x8*)&dst[base] = o0;
  *(bf16x8*)&dst[base + 8] = o1;
}

// ---------------- gemm3: all-bf16, global_load_lds dbuf, swizzled LDS,
// XCD-chunked block swizzle. C(MxN) = A(MxK) @ Bt^T, A [m][k], Bt [n][k].
// BM=128 BN=64 BK=64, 256 thr (4 waves 2x2).
template<int CM>
__global__ __launch_bounds__(256) void gemm3(const short* __restrict__ A, const short* __restrict__ Bt,
                                             void* __restrict__ Cp, int M, int N, int K) {
  __shared__ __align__(16) short Al[2][128 * 64];
  __shared__ __align__(16) short Bl[2][64 * 64];
  const int tid = threadIdx.x;
  const int lane = tid & 63, w = tid >> 6;
  const int wm = w >> 1, wn = w & 1;
  const int lr = lane & 15, g = lane >> 4;

  // XCD-chunked bijective swizzle (nwg % 8 == 0 for all our grids)
  const int flat = blockIdx.y * gridDim.x + blockIdx.x;
  const int nwg = gridDim.x * gridDim.y;
  const int wid = (flat & 7) * (nwg >> 3) + (flat >> 3);
  const int bx = wid % gridDim.x, by = wid / gridDim.x;
  const int m0 = by * 128, n0 = bx * 64;

  f32x4 acc[4][2];
#pragma unroll
  for (int i = 0; i < 4; i++)
#pragma unroll
    for (int j = 0; j < 2; j++) acc[i][j] = (f32x4){0.f, 0.f, 0.f, 0.f};

  const int srow = lane >> 3;
  const int sch = (lane & 7) ^ (srow & 7);
  const short* gA = A + (size_t)(m0 + w * 32 + srow) * K + 8 * sch;
  const short* gB = Bt + (size_t)(n0 + w * 16 + srow) * K + 8 * sch;

#define STAGE(buf, kk)                                                              \
  do {                                                                              \
    _Pragma("unroll") for (int c = 0; c < 4; c++)                                   \
        gload16(gA + (size_t)c * 8 * K + (kk), &Al[buf][(w * 32 + c * 8) * 64]);    \
    _Pragma("unroll") for (int c = 0; c < 2; c++)                                   \
        gload16(gB + (size_t)c * 8 * K + (kk), &Bl[buf][(w * 16 + c * 8) * 64]);    \
  } while (0)

  const int nsteps = K >> 6;
  STAGE(0, 0);
  int buf = 0;
  for (int t = 0; t < nsteps; t++) {
    __syncthreads();
    if (t + 1 < nsteps) STAGE(buf ^ 1, (t + 1) << 6);
#pragma unroll
    for (int kc = 0; kc < 2; kc++) {
      bf16x8 af[4], bfr[2];
#pragma unroll
      for (int mt = 0; mt < 4; mt++) {
        int row = wm * 64 + mt * 16 + lr;
        af[mt] = *(const bf16x8*)&Al[buf][row * 64 + 8 * ((kc * 4 + g) ^ (lr & 7))];
      }
#pragma unroll
      for (int nt = 0; nt < 2; nt++) {
        int row = wn * 32 + nt * 16 + lr;
        bfr[nt] = *(const bf16x8*)&Bl[buf][row * 64 + 8 * ((kc * 4 + g) ^ (lr & 7))];
      }
      __builtin_amdgcn_s_setprio(1);
#pragma unroll
      for (int mt = 0; mt < 4; mt++)
#pragma unroll
        for (int nt = 0; nt < 2; nt++)
          acc[mt][nt] = __builtin_amdgcn_mfma_f32_16x16x32_bf16(af[mt], bfr[nt], acc[mt][nt], 0, 0, 0);
      __builtin_amdgcn_s_setprio(0);
    }
    buf ^= 1;
  }
#undef STAGE

#pragma unroll
  for (int mt = 0; mt < 4; mt++)
#pragma unroll
    for (int nt = 0; nt < 2; nt++)
#pragma unroll
      for (int r = 0; r < 4; r++) {
        int row = m0 + wm * 64 + mt * 16 + g * 4 + r;
        int col = n0 + wn * 32 + nt * 16 + lr;
        if (CM == 0) {
          ((float*)Cp)[(size_t)row * N + col] = acc[mt][nt][r];
        } else if (CM == 1 || CM == 3) {
          float v = (CM == 3) ? acc[mt][nt][r] * 0.18033688011f : acc[mt][nt][r];
          int b = row >> 11, s = row & (S_LEN - 1);
          int h = col >> 6, d = col & 63;
          ((short*)Cp)[(((size_t)(b * NHEAD + h)) * S_LEN + s) * 64 + d] = f2bf(v);
        } else {
          int h = row >> 6, d = row & 63;
          int b = col >> 11, s = col & (S_LEN - 1);
          ((short*)Cp)[(((size_t)(b * NHEAD + h)) * 64 + d) * S_LEN + s] = f2bf(acc[mt][nt][r]);
        }
      }
}

// ---------------- gemm2 (reg-staged, fallback path for small ws)
template<int AM, int BMODE, int CM>
__global__ __launch_bounds__(256) void gemm2(const void* __restrict__ Ap, const void* __restrict__ Bp,
                                             void* __restrict__ Cp, int M, int N, int K) {
  __shared__ __align__(16) short Al[128][72];
  __shared__ __align__(16) short Bl[64][72];
  const int tid = threadIdx.x;
  const int lane = tid & 63, w = tid >> 6;
  const int wm = w >> 1, wn = w & 1;
  const int lr = lane & 15, g = lane >> 4;
  const int m0 = blockIdx.y * 128, n0 = blockIdx.x * 64;

  f32x4 acc[4][2];
#pragma unroll
  for (int i = 0; i < 4; i++)
#pragma unroll
    for (int j = 0; j < 2; j++) acc[i][j] = (f32x4){0.f, 0.f, 0.f, 0.f};

  const int ar = tid >> 1, ac = (tid & 1) * 32;
  const int br = tid >> 2, bc = (tid & 3) * 16;

  float4 la[8]; bf16x8 la8[4];
  float4 lb[4]; bf16x8 lb8[2];

#define LOADA(kk)                                                                        \
  do {                                                                                   \
    if (AM == 0) {                                                                       \
      const float* A = (const float*)Ap;                                                 \
      _Pragma("unroll") for (int j = 0; j < 8; j++)                                      \
          la[j] = *(const float4*)&A[(size_t)(m0 + ar) * K + (kk) + ac + 4 * j];         \
    } else {                                                                             \
      const short* A = (const short*)Ap;                                                 \
      _Pragma("unroll") for (int j = 0; j < 4; j++)                                      \
          la8[j] = *(const bf16x8*)&A[(size_t)(m0 + ar) * K + (kk) + ac + 8 * j];        \
    }                                                                                    \
  } while (0)

#define LOADB(kk)                                                                        \
  do {                                                                                   \
    if (BMODE == 0) {                                                                    \
      const float* B = (const float*)Bp;                                                 \
      _Pragma("unroll") for (int j = 0; j < 4; j++)                                      \
          lb[j] = *(const float4*)&B[(size_t)(n0 + br) * K + (kk) + bc + 4 * j];         \
    } else if (BMODE == 1) {                                                             \
      const short* B = (const short*)Bp;                                                 \
      _Pragma("unroll") for (int j = 0; j < 2; j++)                                      \
          lb8[j] = *(const bf16x8*)&B[(size_t)(n0 + br) * K + (kk) + bc + 8 * j];        \
    } else {                                                                             \
      const float* B = (const float*)Bp;                                                 \
      _Pragma("unroll") for (int j = 0; j < 4; j++)                                      \
          lb[j] = *(const float4*)&B[(size_t)((kk) + br) * N + n0 + bc + 4 * j];         \
    }                                                                                    \
  } while (0)

  const int nsteps = K >> 6;
  LOADA(0); LOADB(0);

  for (int t = 0; t < nsteps; t++) {
    __syncthreads();
    if (AM == 0) {
#pragma unroll
      for (int j = 0; j < 4; j++) {
        float4 v0 = la[2 * j], v1 = la[2 * j + 1];
        bf16x8 tt;
        tt[0] = f2bf(v0.x); tt[1] = f2bf(v0.y); tt[2] = f2bf(v0.z); tt[3] = f2bf(v0.w);
        tt[4] = f2bf(v1.x); tt[5] = f2bf(v1.y); tt[6] = f2bf(v1.z); tt[7] = f2bf(v1.w);
        *(bf16x8*)&Al[ar][ac + 8 * j] = tt;
      }
    } else {
#pragma unroll
      for (int j = 0; j < 4; j++) *(bf16x8*)&Al[ar][ac + 8 * j] = la8[j];
    }
    if (BMODE == 0) {
#pragma unroll
      for (int j = 0; j < 2; j++) {
        float4 v0 = lb[2 * j], v1 = lb[2 * j + 1];
        bf16x8 tt;
        tt[0] = f2bf(v0.x); tt[1] = f2bf(v0.y); tt[2] = f2bf(v0.z); tt[3] = f2bf(v0.w);
        tt[4] = f2bf(v1.x); tt[5] = f2bf(v1.y); tt[6] = f2bf(v1.z); tt[7] = f2bf(v1.w);
        *(bf16x8*)&Bl[br][bc + 8 * j] = tt;
      }
    } else if (BMODE == 1) {
#pragma unroll
      for (int j = 0; j < 2; j++) *(bf16x8*)&Bl[br][bc + 8 * j] = lb8[j];
    } else {
#pragma unroll
      for (int j = 0; j < 4; j++) {
        float4 v = lb[j];
        Bl[bc + 4 * j + 0][br] = f2bf(v.x);
        Bl[bc + 4 * j + 1][br] = f2bf(v.y);
        Bl[bc + 4 * j + 2][br] = f2bf(v.z);
        Bl[bc + 4 * j + 3][br] = f2bf(v.w);
      }
    }
    __syncthreads();
    if (t + 1 < nsteps) { LOADA((t + 1) << 6); LOADB((t + 1) << 6); }
#pragma unroll
    for (int kc = 0; kc < 2; kc++) {
      bf16x8 af[4], bfr[2];
#pragma unroll
      for (int mt = 0; mt < 4; mt++) af[mt] = *(const bf16x8*)&Al[wm * 64 + mt * 16 + lr][kc * 32 + g * 8];
#pragma unroll
      for (int nt = 0; nt < 2; nt++) bfr[nt] = *(const bf16x8*)&Bl[wn * 32 + nt * 16 + lr][kc * 32 + g * 8];
#pragma unroll
      for (int mt = 0; mt < 4; mt++)
#pragma unroll
        for (int nt = 0; nt < 2; nt++)
          acc[mt][nt] = __builtin_amdgcn_mfma_f32_16x16x32_bf16(af[mt], bfr[nt], acc[mt][nt], 0, 0, 0);
    }
  }
#undef LOADA
#undef LOADB

#pragma unroll
  for (int mt = 0; mt < 4; mt++)
#pragma unroll
    for (int nt = 0; nt < 2; nt++)
#pragma unroll
      for (int r = 0; r < 4; r++) {
        int row = m0 + wm * 64 + mt * 16 + g * 4 + r;
        int col = n0 + wn * 32 + nt * 16 + lr;
        if (CM == 0) {
          ((float*)Cp)[(size_t)row * N + col] = acc[mt][nt][r];
        } else if (CM == 1 || CM == 3) {
          float v = (CM == 3) ? acc[mt][nt][r] * 0.18033688011f : acc[mt][nt][r];
          int b = row >> 11, s = row & (S_LEN - 1);
          int h = col >> 6, d = col & 63;
          ((short*)Cp)[(((size_t)(b * NHEAD + h)) * S_LEN + s) * 64 + d] = f2bf(v);
        } else {
          int h = row >> 6, d = row & 63;
          int b = col >> 11, s = col & (S_LEN - 1);
          ((short*)Cp)[(((size_t)(b * NHEAD + h)) * 64 + d) * S_LEN + s] = f2bf(acc[mt][nt][r]);
        }
      }
}

// ---------------- Flash attention v6: attn4 shell (QBLK=128, 4 waves,
// 512 blocks = 2/CU) + swapped QK^T + fully in-register P via
// permlane32/16_swap (no P LDS at all). Q pre-scaled by 0.125*log2e;
// max-free exp2 softmax, deferred row-sum.
// Layouts: S^T frag: lane(lr,g) holds P[q=lr][k=nt*16+4g+r].
// PV A-frag needs P[q=lr][k=kh*32+g*8+j]; achieved by
// (d0,d2)=pl16(pl32(W0[2kh],W0[2kh+1])), (d1,d3)=same on W1.
__global__ __launch_bounds__(256, 2) void attn6(const short* __restrict__ Qb,
                                                const short* __restrict__ Kb,
                                                const short* __restrict__ VbT,
                                                const int* __restrict__ mask,
                                                short* __restrict__ Ob) {
  __shared__ __align__(16) short Kl[2][64][64];
  __shared__ __align__(16) short Vl[2][64][64];

  const int tid = threadIdx.x;
  const int lane = tid & 63, w = tid >> 6;  // 4 waves
  const int lr = lane & 15, g = lane >> 4;

  // XCD-chunked bijective swizzle: 512 blocks, 64/XCD
  const int flat = blockIdx.y * gridDim.x + blockIdx.x;
  const int wid = (flat & 7) * 64 + (flat >> 3);
  const int qblk = wid & 15, bh = wid >> 4;
  const int b = bh >> 4, h = bh & 15;
  const int qbase = qblk * 128;
  const size_t hoff = (size_t)bh * S_LEN * 64;

  bf16x8 qf[2][2];
#pragma unroll
  for (int qfr = 0; qfr < 2; qfr++)
#pragma unroll
    for (int kh = 0; kh < 2; kh++)
      qf[qfr][kh] = *(const bf16x8*)&Qb[hoff + (size_t)(qbase + w * 32 + qfr * 16 + lr) * 64 + kh * 32 + g * 8];

  f32x4 o_acc[2][4];
  float lsum[2];
#pragma unroll
  for (int qfr = 0; qfr < 2; qfr++) {
    lsum[qfr] = 0.f;
#pragma unroll
    for (int dg = 0; dg < 4; dg++) o_acc[qfr][dg] = (f32x4){0.f, 0.f, 0.f, 0.f};
  }

  const int* maskb = mask + b * S_LEN;
  const int srow = lane >> 3;
  const int sch = (lane & 7) ^ (srow & 7);
  const short* gK = Kb + hoff + (size_t)(w * 16 + srow) * 64 + 8 * sch;
  const short* gV = VbT + hoff + (size_t)(w * 16 + srow) * S_LEN + 8 * sch;

#define STAGEKV(buf, kb)                                                         \
  do {                                                                           \
    _Pragma("unroll") for (int c = 0; c < 2; c++)                                \
        gload16(gK + (size_t)(kb + c * 8) * 64, &Kl[buf][w * 16 + c * 8][0]);    \
    _Pragma("unroll") for (int c = 0; c < 2; c++)                                \
        gload16(gV + (size_t)c * 8 * S_LEN + (kb), &Vl[buf][w * 16 + c * 8][0]); \
  } while (0)

  const int NT = S_LEN / 64;
  STAGEKV(0, 0);
  int buf = 0;

  for (int t = 0; t < NT; t++) {
    const int kb = t * 64;
    __syncthreads();  // vmcnt drained: tile t resident; prior reads of buf^1 done
    if (t + 1 < NT) STAGEKV(buf ^ 1, kb + 64);

    // mask bias for k = nt*16 + 4g + r
    float bias[4][4];
#pragma unroll
    for (int nt = 0; nt < 4; nt++) {
      int4 mv = *(const int4*)&maskb[kb + nt * 16 + 4 * g];
      bias[nt][0] = mv.x ? 0.f : -1e30f;
      bias[nt][1] = mv.y ? 0.f : -1e30f;
      bias[nt][2] = mv.z ? 0.f : -1e30f;
      bias[nt][3] = mv.w ? 0.f : -1e30f;
    }

    // K frags (A-operand): K[k=nt*16+lr][d]
    bf16x8 kfr[4][2];
#pragma unroll
    for (int nt = 0; nt < 4; nt++)
#pragma unroll
      for (int kh = 0; kh < 2; kh++)
        kfr[nt][kh] = *(const bf16x8*)&Kl[buf][nt * 16 + lr][8 * ((4 * kh + g) ^ (lr & 7))];

    // V frags (B-operand): V^T[d=dg*16+lr][k]
    bf16x8 vfr[4][2];
#pragma unroll
    for (int dg = 0; dg < 4; dg++)
#pragma unroll
      for (int kh = 0; kh < 2; kh++)
        vfr[dg][kh] = *(const bf16x8*)&Vl[buf][dg * 16 + lr][8 * ((4 * kh + g) ^ (lr & 7))];

#pragma unroll
    for (int qfr = 0; qfr < 2; qfr++) {
      // ---- swapped QK^T: S^T = mfma(K, Q)
      f32x4 s[4];
#pragma unroll
      for (int nt = 0; nt < 4; nt++) s[nt] = (f32x4){0.f, 0.f, 0.f, 0.f};
      __builtin_amdgcn_s_setprio(1);
#pragma unroll
      for (int nt = 0; nt < 4; nt++) {
        s[nt] = __builtin_amdgcn_mfma_f32_16x16x32_bf16(kfr[nt][0], qf[qfr][0], s[nt], 0, 0, 0);
        s[nt] = __builtin_amdgcn_mfma_f32_16x16x32_bf16(kfr[nt][1], qf[qfr][1], s[nt], 0, 0, 0);
      }
      __builtin_amdgcn_s_setprio(0);

      // ---- softmax: p = exp2(s + bias); pack to bf16 pairs
      unsigned W0[4], W1[4];
#pragma unroll
      for (int nt = 0; nt < 4; nt++) {
        float p0 = EXP2(s[nt][0] + bias[nt][0]);
        float p1 = EXP2(s[nt][1] + bias[nt][1]);
        float p2 = EXP2(s[nt][2] + bias[nt][2]);
        float p3 = EXP2(s[nt][3] + bias[nt][3]);
        lsum[qfr] += (p0 + p1) + (p2 + p3);
        W0[nt] = cvt_pk_bf16(p0, p1);
        W1[nt] = cvt_pk_bf16(p2, p3);
      }

      // ---- in-register P redistribution to A-frag layout
      bf16x8 pf[2];
#pragma unroll
      for (int kh = 0; kh < 2; kh++) {
        unsigned a0 = W0[2 * kh], b0 = W0[2 * kh + 1];
        unsigned a1 = W1[2 * kh], b1 = W1[2 * kh + 1];
        pl32swap(a0, b0); pl16swap(a0, b0);  // a0 = d0 (j=0,1), b0 = d2 (j=4,5)
        pl32swap(a1, b1); pl16swap(a1, b1);  // a1 = d1 (j=2,3), b1 = d3 (j=6,7)
        union { unsigned u[4]; bf16x8 v; } pk;
        pk.u[0] = a0; pk.u[1] = a1; pk.u[2] = b0; pk.u[3] = b1;
        pf[kh] = pk.v;
      }

      // ---- PV
      __builtin_amdgcn_s_setprio(1);
#pragma unroll
      for (int dg = 0; dg < 4; dg++) {
        o_acc[qfr][dg] = __builtin_amdgcn_mfma_f32_16x16x32_bf16(pf[0], vfr[dg][0], o_acc[qfr][dg], 0, 0, 0);
        o_acc[qfr][dg] = __builtin_amdgcn_mfma_f32_16x16x32_bf16(pf[1], vfr[dg][1], o_acc[qfr][dg], 0, 0, 0);
      }
      __builtin_amdgcn_s_setprio(0);
    }
    buf ^= 1;
  }
#undef STAGEKV

  // ---- epilogue: lsum per lane covers q=lr; reduce over g, transpose to q=4g+r
#pragma unroll
  for (int qfr = 0; qfr < 2; qfr++) {
    float l = lsum[qfr];
    l += __shfl_xor(l, 16);
    l += __shfl_xor(l, 32);
    float inv = 1.f / l;
    float invq[4];
#pragma unroll
    for (int r = 0; r < 4; r++) invq[r] = __shfl(inv, 4 * g + r);
#pragma unroll
    for (int dg = 0; dg < 4; dg++)
#pragma unroll
      for (int r = 0; r < 4; r++) {
        int qr = qbase + w * 32 + qfr * 16 + 4 * g + r;
        int col = h * 64 + dg * 16 + lr;
        Ob[((size_t)b * S_LEN + qr) * DM + col] = f2bf(o_acc[qfr][dg][r] * invq[r]);
      }
  }
}

extern "C" void kernel_launch(void* const* d_in, const int* in_sizes, int n_in,
                              void* d_out, int out_size, void* d_ws, size_t ws_size,
                              hipStream_t stream) {
  const float* query = (const float*)d_in[0];
  const float* key   = (const float*)d_in[1];
  const float* value = (const float*)d_in[2];
  const float* Wq = (const float*)d_in[3];
  const float* Wk = (const float*)d_in[4];
  const float* Wv = (const float*)d_in[5];
  const float* Wo = (const float*)d_in[6];
  const int* mask = (const int*)d_in[7];

  char* ws = (char*)d_ws;
  const size_t MB = 1 << 20;
  const bool big = ws_size >= 41 * MB;

  dim3 ag(S_LEN / 128, 2 * NHEAD);  // (16, 32) = 512 blocks

  if (big) {
    short* xq  = (short*)(ws);
    short* xk  = (short*)(ws + 8 * MB);
    short* xv  = (short*)(ws + 16 * MB);
    short* WqT = (short*)(ws + 24 * MB);
    short* WkT = (short*)(ws + 26 * MB);
    short* WvT = (short*)(ws + 28 * MB);
    short* WoT = (short*)(ws + 30 * MB);
    short* Qb  = (short*)(ws + 32 * MB);
    short* Kb  = xq;
    short* VbT = xk;
    short* Ob  = xv;

    dim3 tgrid(16, 16, 4);
    wtrans<<<tgrid, 256, 0, stream>>>(Wq, Wk, Wv, Wo, WqT, WkT, WvT, WoT);
    dim3 cg(1024, 3);
    xcvt<<<cg, 256, 0, stream>>>(query, key, value, xq, xk, xv);

    dim3 gqk(DM / 64, (2 * S_LEN) / 128);  // (16, 32) = 512
    gemm3<3><<<gqk, 256, 0, stream>>>(xq, WqT, Qb, 2 * S_LEN, DM, DM);
    gemm3<1><<<gqk, 256, 0, stream>>>(xk, WkT, Kb, 2 * S_LEN, DM, DM);
    dim3 gv((2 * S_LEN) / 64, DM / 128);   // (64, 8) = 512
    gemm3<2><<<gv, 256, 0, stream>>>(WvT, xv, VbT, DM, 2 * S_LEN, DM);

    attn6<<<ag, 256, 0, stream>>>(Qb, Kb, VbT, mask, Ob);

    gemm3<0><<<gqk, 256, 0, stream>>>(Ob, WoT, (float*)d_out, 2 * S_LEN, DM, DM);
  } else {
    short* Qb  = (short*)(ws);
    short* Kb  = (short*)(ws + 8 * MB);
    short* VbT = (short*)(ws + 16 * MB);
    short* WqT = (short*)(ws + 24 * MB);
    short* WkT = (short*)(ws + 26 * MB);
    short* WvT = (short*)(ws + 28 * MB);
    short* Ob  = (short*)(ws + 24 * MB);  // aliases dead WqT/WkT/WvT

    dim3 tgrid(16, 16, 3);
    wtrans<<<tgrid, 256, 0, stream>>>(Wq, Wk, Wv, Wo, WqT, WkT, WvT, WqT);

    dim3 gq(DM / 64, (2 * S_LEN) / 128);
    gemm2<0, 1, 3><<<gq, 256, 0, stream>>>(query, WqT, Qb, 2 * S_LEN, DM, DM);
    gemm2<0, 1, 1><<<gq, 256, 0, stream>>>(key,   WkT, Kb, 2 * S_LEN, DM, DM);
    dim3 gv((2 * S_LEN) / 64, DM / 128);
    gemm2<1, 0, 2><<<gv, 256, 0, stream>>>(WvT, value, VbT, DM, 2 * S_LEN, DM);

    attn6<<<ag, 256, 0, stream>>>(Qb, Kb, VbT, mask, Ob);

    gemm2<1, 2, 0><<<gq, 256, 0, stream>>>(Ob, Wo, (float*)d_out, 2 * S_LEN, DM, DM);
  }
}